// Round 2
// baseline (235.865 us; speedup 1.0000x reference)
//
#include <hip/hip_runtime.h>

// APoT (8-bit, m=2) quantizer, eval forward — bit-logic, divide-free fast path.
//
// Codebook = {0, ±2^-p, ±(2^-p + 2^-q)}: every level is an fp32 with at most
// TWO mantissa bits set, finest bit 2^-15 absolute. Nearest-level with
// searchsorted/argmin-first tie-break == exact integer logic on the bit
// pattern of |xn| (verified absmax == 0.0, R1-R3).
//
// R4: per-element IEEE divide replaced by q0 = x * (1/alpha) + exact-decision
// margin test; rare lanes (|d|<=8, ~1e-6) redo the true divide under exec
// mask -> bit-exact.
//
// R5 post-mortem: cached-everything regressed (91 us vs nt's ~71 us) but the
// counters were diagnostic: VGPR_Count=16 proves the 4 dwordx4 loads were
// serialized (16 regs can't hold 4 in-flight 16B loads); FETCH_SIZE=65.6MB
// (vs 134MB logical) proves the input is ~half-resident in Infinity Cache;
// cached stores evict it (thrash), which is why cached lost to nt.
//
// R6 (this round): asymmetric policy + MLP fix.
//   - loads CACHED: input fits in L3 and is kept warm by the harness re-poison;
//     let reads hit Infinity Cache.
//   - stores NON-TEMPORAL: out is never re-read; nt stores don't evict the
//     L3-resident input (the 6.7 TB/s fill needs no cache residency either).
//   - sched_barrier(0) after the 4 loads: forces all 4 issued before any
//     dependent ALU -> 4 outstanding loads/wave. Costs ~20 VGPRs; free
//     (occupancy unaffected up to 64 VGPRs).
//
// Tie semantics (argmin-first): xn>0 tie -> smaller value; xn<0 -> larger mag.

typedef float vfloat4 __attribute__((ext_vector_type(4)));

__device__ __forceinline__ unsigned apot_pick(unsigned a, unsigned s, int& d) {
    // a = bit pattern of clamped |xn| (<= 0x3F800000). Returns level bits
    // (sign excluded); d = signed distance of 2m from the decision midpoint.
    unsigned q;
    if (a >= 0x38000000u) {               // |xn| >= 2^-15 : ~99.999% of data
        const unsigned e    = a >> 23;          // 112..127
        const unsigned m    = a & 0x7FFFFFu;
        const unsigned base = a - m;            // e<<23
        const unsigned g    = 1u << (135u - e); // finest grid bit (abs 2^-15)
        const unsigned L    = 31u - __clz(m | 1u);
        const unsigned bit  = 1u << L;
        const bool fine = (m < g);
        const unsigned lo  = fine ? base       : (base | bit);
        const unsigned hi  = fine ? (base + g) : (base + (bit << 1));
        const unsigned mid = fine ? g : (bit + (bit << 1));
        d = (int)(m + m) - (int)mid;
        const bool pickLo = (d < 0) | ((d == 0) & (s == 0u));
        q = pickLo ? lo : hi;
    } else {
        // |xn| < 2^-15: neighbors {0, 2^-15}; midpoint 2^-16
        d = (int)a - (int)0x37800000u;
        const bool pickZero = (d < 0) | ((d == 0) & (s == 0u));
        q = pickZero ? 0u : 0x38000000u;
    }
    return q;
}

__device__ __forceinline__ float apot_q1(float xv, float r, float alpha_pos) {
    // fast path: approximate quotient, exact-decision margin test
    const float q0 = xv * r;
    float xn = fminf(1.0f, fmaxf(-1.0f, q0));
    unsigned u = __float_as_uint(xn);
    unsigned s = u & 0x80000000u;
    int d;
    unsigned q = apot_pick(u & 0x7FFFFFFFu, s, d);
    if (d < 9 && d > -9) {
        // within margin of a decision boundary: redo with exact IEEE divide
        const float xe = fminf(1.0f, fmaxf(-1.0f, xv / alpha_pos));
        const unsigned ue = __float_as_uint(xe);
        s = ue & 0x80000000u;
        q = apot_pick(ue & 0x7FFFFFFFu, s, d);
    }
    return __uint_as_float(q | s) * alpha_pos;
}

__device__ __forceinline__ vfloat4 quant4(vfloat4 v, float r, float alpha_pos) {
    vfloat4 o;
    #pragma unroll
    for (int e = 0; e < 4; ++e) o[e] = apot_q1(v[e], r, alpha_pos);
    return o;
}

// One-shot blocks, 16 elems/thread. Cached loads (L3-resident input),
// non-temporal stores (no L3 pollution), all 4 dwordx4 loads pinned in
// flight via sched_barrier before any dependent ALU.
__global__ __launch_bounds__(256) void apot_quant_kernel(
    const float* __restrict__ x,
    const float* __restrict__ alpha,
    float* __restrict__ out,
    int n)
{
    const float alpha_pos = fabsf(alpha[0]) + 1e-5f;
    const float r = 1.0f / alpha_pos;   // uniform: one divide per thread

    const int blockStart = blockIdx.x * (256 * 16);
    const int i0 = blockStart + (int)threadIdx.x * 4;

    if (blockStart + 256 * 16 <= n) {
        const vfloat4 v0 = *(const vfloat4*)(x + i0);
        const vfloat4 v1 = *(const vfloat4*)(x + i0 + 1024);
        const vfloat4 v2 = *(const vfloat4*)(x + i0 + 2048);
        const vfloat4 v3 = *(const vfloat4*)(x + i0 + 3072);
        // Pin all four loads above any dependent ALU: guarantees 4
        // outstanding vmem ops per wave (R5 showed VGPR_Count=16 -> MLP=1).
        __builtin_amdgcn_sched_barrier(0);
        __builtin_nontemporal_store(quant4(v0, r, alpha_pos), (vfloat4*)(out + i0));
        __builtin_nontemporal_store(quant4(v1, r, alpha_pos), (vfloat4*)(out + i0 + 1024));
        __builtin_nontemporal_store(quant4(v2, r, alpha_pos), (vfloat4*)(out + i0 + 2048));
        __builtin_nontemporal_store(quant4(v3, r, alpha_pos), (vfloat4*)(out + i0 + 3072));
    } else {
        // generic tail (not hit for 4096x8192: n % 4096 == 0)
        for (int t = 0; t < 4; ++t) {
            for (int e = 0; e < 4; ++e) {
                const int idx = i0 + t * 1024 + e;
                if (idx < n) out[idx] = apot_q1(x[idx], r, alpha_pos);
            }
        }
    }
}

extern "C" void kernel_launch(void* const* d_in, const int* in_sizes, int n_in,
                              void* d_out, int out_size, void* d_ws, size_t ws_size,
                              hipStream_t stream) {
    const float* x     = (const float*)d_in[0];
    const float* alpha = (const float*)d_in[1];
    // d_in[2] (codebook) is implied by the bit logic; not read.
    float* out         = (float*)d_out;

    const int n = in_sizes[0];            // 33,554,432
    const int elemsPerBlock = 256 * 16;
    const int grid = (n + elemsPerBlock - 1) / elemsPerBlock;  // 8192

    apot_quant_kernel<<<grid, 256, 0, stream>>>(x, alpha, out, n);
}

// Round 3
// 225.355 us; speedup vs baseline: 1.0466x; 1.0466x over previous
//
#include <hip/hip_runtime.h>

// APoT (8-bit, m=2) quantizer, eval forward — bit-logic, divide-free fast path.
//
// Codebook = {0, ±2^-p, ±(2^-p + 2^-q)}: every level is an fp32 with at most
// TWO mantissa bits set, finest bit 2^-15 absolute. Nearest-level with
// searchsorted/argmin-first tie-break == exact integer logic on the bit
// pattern of |xn| (verified absmax == 0.0, R1-R3).
//
// R4: per-element IEEE divide replaced by q0 = x * (1/alpha) + exact-decision
// margin test; rare lanes (|d|<=8, ~1e-6) redo the true divide under exec
// mask -> bit-exact.  R4 config (nt loads + nt stores) = best known, ~71 us.
//
// R5/R6 post-mortem: cached loads regressed vs nt (80-91 vs 71 us) despite
// FETCH_SIZE=65.6MB proving half the input is L3-resident -> kernel is
// latency/schedule-bound, not BW-bound. VGPR_Count=16 in BOTH rounds proves
// the compiler serializes the 4 dwordx4 loads (16 regs cannot hold 4 live
// 16B results); sched_barrier(0) did NOT fix it (scheduling hint, but RA
// still interleaved load->use pairs).
//
// R7 (this round): force MLP=4 via DATA LIVENESS, not scheduling hints.
// An asm read-write of all four loaded vectors before any compute makes all
// four simultaneously live -> allocator must assign distinct quads -> the
// four global_load_dwordx4 issue back-to-back with one s_waitcnt, amortizing
// ~900cy HBM latency 4x. Verification: VGPR_Count must jump to ~36-48.
// Load/store policy reverted to R4's nt/nt (best baseline) so this is a
// single-variable experiment.
//
// Tie semantics (argmin-first): xn>0 tie -> smaller value; xn<0 -> larger mag.

typedef float vfloat4 __attribute__((ext_vector_type(4)));

__device__ __forceinline__ unsigned apot_pick(unsigned a, unsigned s, int& d) {
    // a = bit pattern of clamped |xn| (<= 0x3F800000). Returns level bits
    // (sign excluded); d = signed distance of 2m from the decision midpoint.
    unsigned q;
    if (a >= 0x38000000u) {               // |xn| >= 2^-15 : ~99.999% of data
        const unsigned e    = a >> 23;          // 112..127
        const unsigned m    = a & 0x7FFFFFu;
        const unsigned base = a - m;            // e<<23
        const unsigned g    = 1u << (135u - e); // finest grid bit (abs 2^-15)
        const unsigned L    = 31u - __clz(m | 1u);
        const unsigned bit  = 1u << L;
        const bool fine = (m < g);
        const unsigned lo  = fine ? base       : (base | bit);
        const unsigned hi  = fine ? (base + g) : (base + (bit << 1));
        const unsigned mid = fine ? g : (bit + (bit << 1));
        d = (int)(m + m) - (int)mid;
        const bool pickLo = (d < 0) | ((d == 0) & (s == 0u));
        q = pickLo ? lo : hi;
    } else {
        // |xn| < 2^-15: neighbors {0, 2^-15}; midpoint 2^-16
        d = (int)a - (int)0x37800000u;
        const bool pickZero = (d < 0) | ((d == 0) & (s == 0u));
        q = pickZero ? 0u : 0x38000000u;
    }
    return q;
}

__device__ __forceinline__ float apot_q1(float xv, float r, float alpha_pos) {
    // fast path: approximate quotient, exact-decision margin test
    const float q0 = xv * r;
    float xn = fminf(1.0f, fmaxf(-1.0f, q0));
    unsigned u = __float_as_uint(xn);
    unsigned s = u & 0x80000000u;
    int d;
    unsigned q = apot_pick(u & 0x7FFFFFFFu, s, d);
    if (d < 9 && d > -9) {
        // within margin of a decision boundary: redo with exact IEEE divide
        const float xe = fminf(1.0f, fmaxf(-1.0f, xv / alpha_pos));
        const unsigned ue = __float_as_uint(xe);
        s = ue & 0x80000000u;
        q = apot_pick(ue & 0x7FFFFFFFu, s, d);
    }
    return __uint_as_float(q | s) * alpha_pos;
}

__device__ __forceinline__ vfloat4 quant4(vfloat4 v, float r, float alpha_pos) {
    vfloat4 o;
    #pragma unroll
    for (int e = 0; e < 4; ++e) o[e] = apot_q1(v[e], r, alpha_pos);
    return o;
}

// One-shot blocks, 16 elems/thread, nt loads + nt stores (R4 best config),
// MLP=4 forced via asm liveness of all four loaded vectors.
__global__ __launch_bounds__(256) void apot_quant_kernel(
    const float* __restrict__ x,
    const float* __restrict__ alpha,
    float* __restrict__ out,
    int n)
{
    const float alpha_pos = fabsf(alpha[0]) + 1e-5f;
    const float r = 1.0f / alpha_pos;   // uniform: one divide per thread

    const int blockStart = blockIdx.x * (256 * 16);
    const int i0 = blockStart + (int)threadIdx.x * 4;

    if (blockStart + 256 * 16 <= n) {
        vfloat4 v0 = __builtin_nontemporal_load((const vfloat4*)(x + i0));
        vfloat4 v1 = __builtin_nontemporal_load((const vfloat4*)(x + i0 + 1024));
        vfloat4 v2 = __builtin_nontemporal_load((const vfloat4*)(x + i0 + 2048));
        vfloat4 v3 = __builtin_nontemporal_load((const vfloat4*)(x + i0 + 3072));
        // Force all four results simultaneously live: the register allocator
        // must give them distinct quads, so all four loads issue before any
        // dependent ALU (R5/R6: VGPR_Count=16 proved load->use serialization;
        // expect ~36-48 now).
        asm volatile("" : "+v"(v0), "+v"(v1), "+v"(v2), "+v"(v3));
        __builtin_nontemporal_store(quant4(v0, r, alpha_pos), (vfloat4*)(out + i0));
        __builtin_nontemporal_store(quant4(v1, r, alpha_pos), (vfloat4*)(out + i0 + 1024));
        __builtin_nontemporal_store(quant4(v2, r, alpha_pos), (vfloat4*)(out + i0 + 2048));
        __builtin_nontemporal_store(quant4(v3, r, alpha_pos), (vfloat4*)(out + i0 + 3072));
    } else {
        // generic tail (not hit for 4096x8192: n % 4096 == 0)
        for (int t = 0; t < 4; ++t) {
            for (int e = 0; e < 4; ++e) {
                const int idx = i0 + t * 1024 + e;
                if (idx < n) out[idx] = apot_q1(x[idx], r, alpha_pos);
            }
        }
    }
}

extern "C" void kernel_launch(void* const* d_in, const int* in_sizes, int n_in,
                              void* d_out, int out_size, void* d_ws, size_t ws_size,
                              hipStream_t stream) {
    const float* x     = (const float*)d_in[0];
    const float* alpha = (const float*)d_in[1];
    // d_in[2] (codebook) is implied by the bit logic; not read.
    float* out         = (float*)d_out;

    const int n = in_sizes[0];            // 33,554,432
    const int elemsPerBlock = 256 * 16;
    const int grid = (n + elemsPerBlock - 1) / elemsPerBlock;  // 8192

    apot_quant_kernel<<<grid, 256, 0, stream>>>(x, alpha, out, n);
}

// Round 4
// 224.785 us; speedup vs baseline: 1.0493x; 1.0025x over previous
//
#include <hip/hip_runtime.h>

// APoT (8-bit, m=2) quantizer, eval forward — bit-logic, divide-free fast path.
//
// Codebook = {0, ±2^-p, ±(2^-p + 2^-q)}: every level is an fp32 with at most
// TWO mantissa bits set, finest bit 2^-15 absolute. Nearest-level with
// searchsorted/argmin-first tie-break == exact integer logic on the bit
// pattern of |xn| (verified absmax == 0.0, R1-R3).
//
// R4: per-element IEEE divide replaced by q0 = x * (1/alpha) + exact-decision
// margin test; rare lanes (|d|<=8, ~1e-6) redo the true divide under exec
// mask -> bit-exact.
//
// Policy ablation history (kernel dispatch time):
//   nt load + nt store      : 65-71 us  (R4/R7 best)
//   cached load + nt store  : 80 us     (R6)
//   cached load + cached st : 91 us     (R5)
//   nt load + cached store  : THIS ROUND (R8)
// Rationale: both ceiling-achieving references on this chip (512MiB fill
// @6.7 TB/s, float4 copy @6.29 TB/s) use CACHED stores — L2 aggregates and
// write-backs full lines. R5's cached-store penalty was L3-input eviction,
// a mechanism that vanishes with nt loads. R7's asm-liveness (MLP=4) was
// neutral -> per-wave MLP not binding; kept for A/B continuity.
//
// Tie semantics (argmin-first): xn>0 tie -> smaller value; xn<0 -> larger mag.

typedef float vfloat4 __attribute__((ext_vector_type(4)));

__device__ __forceinline__ unsigned apot_pick(unsigned a, unsigned s, int& d) {
    // a = bit pattern of clamped |xn| (<= 0x3F800000). Returns level bits
    // (sign excluded); d = signed distance of 2m from the decision midpoint.
    unsigned q;
    if (a >= 0x38000000u) {               // |xn| >= 2^-15 : ~99.999% of data
        const unsigned e    = a >> 23;          // 112..127
        const unsigned m    = a & 0x7FFFFFu;
        const unsigned base = a - m;            // e<<23
        const unsigned g    = 1u << (135u - e); // finest grid bit (abs 2^-15)
        const unsigned L    = 31u - __clz(m | 1u);
        const unsigned bit  = 1u << L;
        const bool fine = (m < g);
        const unsigned lo  = fine ? base       : (base | bit);
        const unsigned hi  = fine ? (base + g) : (base + (bit << 1));
        const unsigned mid = fine ? g : (bit + (bit << 1));
        d = (int)(m + m) - (int)mid;
        const bool pickLo = (d < 0) | ((d == 0) & (s == 0u));
        q = pickLo ? lo : hi;
    } else {
        // |xn| < 2^-15: neighbors {0, 2^-15}; midpoint 2^-16
        d = (int)a - (int)0x37800000u;
        const bool pickZero = (d < 0) | ((d == 0) & (s == 0u));
        q = pickZero ? 0u : 0x38000000u;
    }
    return q;
}

__device__ __forceinline__ float apot_q1(float xv, float r, float alpha_pos) {
    // fast path: approximate quotient, exact-decision margin test
    const float q0 = xv * r;
    float xn = fminf(1.0f, fmaxf(-1.0f, q0));
    unsigned u = __float_as_uint(xn);
    unsigned s = u & 0x80000000u;
    int d;
    unsigned q = apot_pick(u & 0x7FFFFFFFu, s, d);
    if (d < 9 && d > -9) {
        // within margin of a decision boundary: redo with exact IEEE divide
        const float xe = fminf(1.0f, fmaxf(-1.0f, xv / alpha_pos));
        const unsigned ue = __float_as_uint(xe);
        s = ue & 0x80000000u;
        q = apot_pick(ue & 0x7FFFFFFFu, s, d);
    }
    return __uint_as_float(q | s) * alpha_pos;
}

__device__ __forceinline__ vfloat4 quant4(vfloat4 v, float r, float alpha_pos) {
    vfloat4 o;
    #pragma unroll
    for (int e = 0; e < 4; ++e) o[e] = apot_q1(v[e], r, alpha_pos);
    return o;
}

// One-shot blocks, 16 elems/thread. nt loads (best measured read path),
// CACHED stores (match the 6.7 TB/s fill's write path), 4 loads pinned
// live via asm.
__global__ __launch_bounds__(256) void apot_quant_kernel(
    const float* __restrict__ x,
    const float* __restrict__ alpha,
    float* __restrict__ out,
    int n)
{
    const float alpha_pos = fabsf(alpha[0]) + 1e-5f;
    const float r = 1.0f / alpha_pos;   // uniform: one divide per thread

    const int blockStart = blockIdx.x * (256 * 16);
    const int i0 = blockStart + (int)threadIdx.x * 4;

    if (blockStart + 256 * 16 <= n) {
        vfloat4 v0 = __builtin_nontemporal_load((const vfloat4*)(x + i0));
        vfloat4 v1 = __builtin_nontemporal_load((const vfloat4*)(x + i0 + 1024));
        vfloat4 v2 = __builtin_nontemporal_load((const vfloat4*)(x + i0 + 2048));
        vfloat4 v3 = __builtin_nontemporal_load((const vfloat4*)(x + i0 + 3072));
        // Keep all four results simultaneously live (MLP=4; neutral in R7
        // but retained so R8 is a single-variable store-policy experiment).
        asm volatile("" : "+v"(v0), "+v"(v1), "+v"(v2), "+v"(v3));
        *(vfloat4*)(out + i0)        = quant4(v0, r, alpha_pos);
        *(vfloat4*)(out + i0 + 1024) = quant4(v1, r, alpha_pos);
        *(vfloat4*)(out + i0 + 2048) = quant4(v2, r, alpha_pos);
        *(vfloat4*)(out + i0 + 3072) = quant4(v3, r, alpha_pos);
    } else {
        // generic tail (not hit for 4096x8192: n % 4096 == 0)
        for (int t = 0; t < 4; ++t) {
            for (int e = 0; e < 4; ++e) {
                const int idx = i0 + t * 1024 + e;
                if (idx < n) out[idx] = apot_q1(x[idx], r, alpha_pos);
            }
        }
    }
}

extern "C" void kernel_launch(void* const* d_in, const int* in_sizes, int n_in,
                              void* d_out, int out_size, void* d_ws, size_t ws_size,
                              hipStream_t stream) {
    const float* x     = (const float*)d_in[0];
    const float* alpha = (const float*)d_in[1];
    // d_in[2] (codebook) is implied by the bit logic; not read.
    float* out         = (float*)d_out;

    const int n = in_sizes[0];            // 33,554,432
    const int elemsPerBlock = 256 * 16;
    const int grid = (n + elemsPerBlock - 1) / elemsPerBlock;  // 8192

    apot_quant_kernel<<<grid, 256, 0, stream>>>(x, alpha, out, n);
}